// Round 10
// baseline (254.355 us; speedup 1.0000x reference)
//
#include <hip/hip_runtime.h>
#include <stdint.h>

// Problem constants
#define B_SZ 1024
#define Z_SZ 32768
#define D_SZ 128
#define NZ   64                 // z chunks (split-Z)
#define CZ   (Z_SZ / NZ)        // 512 z per chunk
#define TZ   64                 // z per inner tile
#define ITERS (CZ / TZ)         // 8
#define TBLK 128                // batch rows per block (4 waves x 32)
#define NWAVE 4
#define WROWS 32                // batch rows per wave (32x32 MFMA cols)
#define ZW   (Z_SZ / 32)        // 1024 mask words per row

// LDS strides (elements). Row byte-strides must be 16B multiples for ds_read_b128,
// and every stride must be >= the row's element count.
#define SEMB_STRIDE  136        // 64 x 136 bf16 (row-major emb tile), 272B rows
#define SEMBT_STRIDE 72         // 128 x 72 bf16 (transposed emb tile), 144B rows
#define ST_STRIDE    136        // prep transpose staging rows hold 128 elems

// prep grid split (R4-verified structure)
#define NB_MASK ((B_SZ * ZW) / 256)   // 4096 blocks pack the bitmask
#define NB_TAB  (Z_SZ / 64)           // 512 blocks build bf16 tables

// Workspace layout (float offsets)
#define WS_O   0                              // [NZ][B][D]  (33.5 MB)
#define WS_M   (NZ * B_SZ * D_SZ)             // [NZ][B]
#define WS_L   (WS_M + NZ * B_SZ)
#define WS_C   (WS_L + NZ * B_SZ)
#define WS_TAB (WS_C + NZ * B_SZ)             // embR [Z][D] bf16, embT [D][Z] bf16, mask [B][ZW] u32

typedef short bf16x8  __attribute__((ext_vector_type(8)));
typedef float f32x4   __attribute__((ext_vector_type(4)));
typedef float f32x16  __attribute__((ext_vector_type(16)));

#if __has_builtin(__builtin_amdgcn_exp2f)
#define EXP2F(x) __builtin_amdgcn_exp2f(x)
#else
#define EXP2F(x) exp2f(x)
#endif

__device__ __forceinline__ unsigned short f2bf(float f) {
    union { float f; uint32_t u; } v; v.f = f;
    uint32_t u = v.u;
    u = (u + 0x7FFFu + ((u >> 16) & 1u)) >> 16;   // RNE truncate to bf16
    return (unsigned short)u;
}
__device__ __forceinline__ uint32_t packbf(float a, float b) {
    return (uint32_t)f2bf(a) | ((uint32_t)f2bf(b) << 16);
}

// ---------------------------------------------------------------------------
// Fused prep (R4-verified):
//   blocks [0, NB_MASK):       z_sparse -> bitmask  (pure BW streaming)
//   blocks [NB_MASK, +NB_TAB): emb f32 -> bf16 embR [Z][D] and embT [D][Z]
// ---------------------------------------------------------------------------
__global__ __launch_bounds__(256) void prep(
    const int*      __restrict__ zs,
    const float*    __restrict__ emb,
    unsigned short* __restrict__ embR,
    unsigned short* __restrict__ embT,
    uint32_t*       __restrict__ maskp)
{
    __shared__ __align__(16) unsigned short st[64 * ST_STRIDE];
    if (blockIdx.x < NB_MASK) {
        // ---- bitmask pack: thread packs 32 consecutive z of one row into one u32 ----
        const int gid = blockIdx.x * 256 + threadIdx.x;       // == b*ZW + w ; b*Z_SZ == gid*32
        const int4* src = (const int4*)(zs + (size_t)gid * 32);
        uint32_t mbits = 0;
#pragma unroll
        for (int k = 0; k < 8; ++k) {
            int4 v = src[k];
            mbits |= (v.x > 0 ? 1u : 0u) << (4 * k + 0);
            mbits |= (v.y > 0 ? 1u : 0u) << (4 * k + 1);
            mbits |= (v.z > 0 ? 1u : 0u) << (4 * k + 2);
            mbits |= (v.w > 0 ? 1u : 0u) << (4 * k + 3);
        }
        maskp[gid] = mbits;
        return;
    }

    // ---- bf16 tables for one 64-z tile ----
    const int z0 = (blockIdx.x - NB_MASK) * 64;
    const int t  = threadIdx.x;
    {
        const int r = t >> 2, q = t & 3;
        const float* src = emb + (size_t)(z0 + r) * D_SZ + q * 32;
        unsigned short* dR = embR + (size_t)(z0 + r) * D_SZ + q * 32;
        unsigned short* dL = st + r * ST_STRIDE + q * 32;
#pragma unroll
        for (int u = 0; u < 8; ++u) {
            float4 x = *(const float4*)(src + 4 * u);
            ushort4 h;
            h.x = f2bf(x.x); h.y = f2bf(x.y); h.z = f2bf(x.z); h.w = f2bf(x.w);
            *(ushort4*)(dR + 4 * u) = h;
            *(ushort4*)(dL + 4 * u) = h;
        }
    }
    __syncthreads();
    {
        const int lane = t & 63, w = t >> 6;
#pragma unroll
        for (int i = 0; i < 4; ++i) {
            const int d = w * 32 + i * 8 + (lane >> 3);   // 0..127
            const int c = lane & 7;                       // 8-z chunk
            bf16x8 v;
#pragma unroll
            for (int k = 0; k < 8; ++k) v[k] = (short)st[(c * 8 + k) * ST_STRIDE + d];
            *(bf16x8*)(embT + (size_t)d * Z_SZ + z0 + c * 8) = v;
        }
    }
}

// ---------------------------------------------------------------------------
// attn_part: 32x32x16 MFMA, double-buffered LDS, ONE barrier per tile,
//            in-register P exchange, BITMASK mask path (1 uint2/lane/tile).
//   GEMM1: sfr[nt] = mfma32(embR_rows, ctx)  -> lane(hi,l31) holds
//          S[b=l31][z' = 32nt + 8g + 4hi + e]   (reg r = 4g+e)
//   mask:  word nt of uint2; bit index = 8g + 4hi + e
//   softmax: in-lane over 32 + ONE shfl_xor(32); T13 defer-max (THR=8)
//   GEMM2 (O^T): acc[nt2] = mfma32(embT_rows, P^T) -> lane holds O[d][b=l31]
// ---------------------------------------------------------------------------
__global__ __launch_bounds__(256, 2) void attn_part(
    const uint32_t*       __restrict__ maskp,
    const float*          __restrict__ ctx,
    const unsigned short* __restrict__ embR,
    const unsigned short* __restrict__ embT,
    float*                __restrict__ ws)
{
    __shared__ __align__(16) unsigned short s_embA [2][TZ   * SEMB_STRIDE];   // 2x17408 B
    __shared__ __align__(16) unsigned short s_embTA[2][D_SZ * SEMBT_STRIDE];  // 2x18432 B

    const int tid  = threadIdx.x;
    const int lane = tid & 63;
    const int l31  = lane & 31;
    const int hi   = lane >> 5;

    const int bg     = blockIdx.x;            // 0..7 batch group
    const int ch     = blockIdx.y;            // 0..63 z-chunk
    const int z_base = ch * CZ;
    const int wb0    = bg * TBLK + (tid >> 6) * WROWS;
    const int brow   = wb0 + l31;             // this lane's batch row (32 rows/wave)

    // staging thread mappings (256 threads, 64B each per tile)
    const int srow = tid >> 2, sq3 = tid & 3;   // row tile: row, 32-elem seg
    const int sd   = tid >> 1, sh  = tid & 1;   // transposed tile: d-row, 32-z seg

    const uint32_t* mrow = maskp + (size_t)brow * ZW;   // lane's mask-word row

    // ---- ctx B-fragments, scaled by log2(e)/sqrt(D) (base-2 softmax), in regs ----
    bf16x8 afrag[8];
    {
        const float scale = (float)(1.4426950408889634 * 0.08838834764831845);
        const float* crow = ctx + (size_t)brow * D_SZ;
#pragma unroll
        for (int ks = 0; ks < 8; ++ks) {
            const float* p = crow + ks * 16 + hi * 8;
            float4 x0 = *(const float4*)(p);
            float4 x1 = *(const float4*)(p + 4);
            bf16x8 a;
            a[0] = (short)f2bf(x0.x * scale); a[1] = (short)f2bf(x0.y * scale);
            a[2] = (short)f2bf(x0.z * scale); a[3] = (short)f2bf(x0.w * scale);
            a[4] = (short)f2bf(x1.x * scale); a[5] = (short)f2bf(x1.y * scale);
            a[6] = (short)f2bf(x1.z * scale); a[7] = (short)f2bf(x1.w * scale);
            afrag[ks] = a;
        }
    }

    // ---- per-lane online-softmax state ----
    float m_s = -1e30f, l_s = 0.f;
    int   cnt = 0;      // FULL per-row count per tile via popc (identical across hi)
    f32x16 acc[4];
#pragma unroll
    for (int n = 0; n < 4; ++n)
#pragma unroll
        for (int e = 0; e < 16; ++e) acc[n][e] = 0.f;

    // ---- staging registers (tables) + mask prefetch ----
    bf16x8 rA[4], rT[4];
    uint2  mv, mvn;

    // prologue: load tile 0 -> regs; write buf0; load tile 1 -> regs; mask tile 0
    {
        const unsigned short* srcR = embR + (size_t)(z_base + srow) * D_SZ + sq3 * 32;
        const unsigned short* srcT = embT + (size_t)sd * Z_SZ + z_base + sh * 32;
#pragma unroll
        for (int u = 0; u < 4; ++u) { rA[u] = *(const bf16x8*)(srcR + u * 8); }
#pragma unroll
        for (int u = 0; u < 4; ++u) { rT[u] = *(const bf16x8*)(srcT + u * 8); }
        mv = *(const uint2*)(mrow + (z_base >> 5));
    }
    {
        unsigned short* dA = s_embA[0] + srow * SEMB_STRIDE + sq3 * 32;
        unsigned short* dT = s_embTA[0] + sd * SEMBT_STRIDE + sh * 32;
#pragma unroll
        for (int u = 0; u < 4; ++u) *(bf16x8*)(dA + u * 8) = rA[u];
#pragma unroll
        for (int u = 0; u < 4; ++u) *(bf16x8*)(dT + u * 8) = rT[u];
    }
    if (ITERS > 1) {
        const int z1 = z_base + TZ;
        const unsigned short* srcR = embR + (size_t)(z1 + srow) * D_SZ + sq3 * 32;
        const unsigned short* srcT = embT + (size_t)sd * Z_SZ + z1 + sh * 32;
#pragma unroll
        for (int u = 0; u < 4; ++u) { rA[u] = *(const bf16x8*)(srcR + u * 8); }
#pragma unroll
        for (int u = 0; u < 4; ++u) { rT[u] = *(const bf16x8*)(srcT + u * 8); }
    }

    int cur = 0;
    for (int it = 0; it < ITERS; ++it) {
        __syncthreads();   // buf[cur] writes visible; prior reads of buf[cur^1] done

        // ---- issue next tile's mask load (one uint2); consumed NEXT iteration ----
        if (it + 1 < ITERS) {
            mvn = *(const uint2*)(mrow + ((z_base + (it + 1) * TZ) >> 5));
        }

        const unsigned short* se = s_embA[cur];
        const unsigned short* st_ = s_embTA[cur];

        // ---- GEMM1 (32x32x16): lane gets S[b=l31][z' = 32nt + 8g + 4hi + e] ----
        f32x16 sfr[2];
#pragma unroll
        for (int nt = 0; nt < 2; ++nt) {
            f32x16 c;
#pragma unroll
            for (int e = 0; e < 16; ++e) c[e] = 0.f;
            const unsigned short* bb = se + (nt * 32 + l31) * SEMB_STRIDE + hi * 8;
#pragma unroll
            for (int ks = 0; ks < 8; ++ks) {
                bf16x8 ef = *(const bf16x8*)(bb + ks * 16);
                c = __builtin_amdgcn_mfma_f32_32x32x16_bf16(ef, afrag[ks], c, 0, 0, 0);
            }
            sfr[nt] = c;
        }

        // ---- mask bits from words: bit index of reg r=4g+e in word nt = 8g+4hi+e ----
        const uint32_t wsh[2] = { mv.x >> (4 * hi), mv.y >> (4 * hi) };
        int bit[2][16];
#pragma unroll
        for (int nt = 0; nt < 2; ++nt) {
#pragma unroll
            for (int g = 0; g < 4; ++g) {
                bit[nt][4*g+0] = (int)((wsh[nt] >> (8*g + 0)) & 1u);
                bit[nt][4*g+1] = (int)((wsh[nt] >> (8*g + 1)) & 1u);
                bit[nt][4*g+2] = (int)((wsh[nt] >> (8*g + 2)) & 1u);
                bit[nt][4*g+3] = (int)((wsh[nt] >> (8*g + 3)) & 1u);
            }
        }
        cnt += __popc(mv.x) + __popc(mv.y);   // full row count for this tile

        // ---- masked max: in-lane tree over 32 + ONE cross-half shuffle ----
        float tm = -1e30f;
#pragma unroll
        for (int nt = 0; nt < 2; ++nt) {
#pragma unroll
            for (int r = 0; r < 16; r += 4) {
                float a0 = bit[nt][r+0] ? sfr[nt][r+0] : -1e30f;
                float a1 = bit[nt][r+1] ? sfr[nt][r+1] : -1e30f;
                float a2 = bit[nt][r+2] ? sfr[nt][r+2] : -1e30f;
                float a3 = bit[nt][r+3] ? sfr[nt][r+3] : -1e30f;
                tm = fmaxf(tm, fmaxf(fmaxf(a0, a1), fmaxf(a2, a3)));
            }
        }
        tm = fmaxf(tm, __shfl_xor(tm, 32));

        // ---- T13 defer-max ----
        if (__any(tm > m_s + 8.f)) {
            float mnew = fmaxf(m_s, tm);
            float al = EXP2F(m_s - mnew);
            m_s = mnew;
            l_s *= al;
#pragma unroll
            for (int n = 0; n < 4; ++n)
#pragma unroll
                for (int e = 0; e < 16; ++e) acc[n][e] *= al;
        }

        // ---- P = mask ? 2^(S-m) : 0 ; pack to u32 bf16-pairs (in-register) ----
        uint32_t q[8][2];
        float ps = 0.f;
#pragma unroll
        for (int nt = 0; nt < 2; ++nt) {
#pragma unroll
            for (int g = 0; g < 4; ++g) {
                float p0 = bit[nt][4*g+0] ? EXP2F(sfr[nt][4*g+0] - m_s) : 0.f;
                float p1 = bit[nt][4*g+1] ? EXP2F(sfr[nt][4*g+1] - m_s) : 0.f;
                float p2 = bit[nt][4*g+2] ? EXP2F(sfr[nt][4*g+2] - m_s) : 0.f;
                float p3 = bit[nt][4*g+3] ? EXP2F(sfr[nt][4*g+3] - m_s) : 0.f;
                ps += (p0 + p1) + (p2 + p3);
                q[4*nt+g][0] = packbf(p0, p1);
                q[4*nt+g][1] = packbf(p2, p3);
            }
        }
        ps += __shfl_xor(ps, 32);
        l_s += ps;

        // ---- assemble GEMM2 B-frags: swap partner half-groups via shfl_xor(32) ----
        bf16x8 pfrag[4];
#pragma unroll
        for (int ks2 = 0; ks2 < 4; ++ks2) {
            uint32_t s0 = hi ? q[2*ks2][0] : q[2*ks2+1][0];   // what partner needs
            uint32_t s1 = hi ? q[2*ks2][1] : q[2*ks2+1][1];
            uint32_t r0 = (uint32_t)__shfl_xor((int)s0, 32);
            uint32_t r1 = (uint32_t)__shfl_xor((int)s1, 32);
            union { uint32_t u[4]; bf16x8 v; } P;
            P.u[0] = hi ? r0 : q[2*ks2][0];     // j=0,1
            P.u[1] = hi ? r1 : q[2*ks2][1];     // j=2,3
            P.u[2] = hi ? q[2*ks2+1][0] : r0;   // j=4,5
            P.u[3] = hi ? q[2*ks2+1][1] : r1;   // j=6,7
            pfrag[ks2] = P.v;
        }

        // ---- GEMM2 (O^T, 32x32x16): acc[nt2] += embT_rows @ P^T ----
#pragma unroll
        for (int nt2 = 0; nt2 < 4; ++nt2) {
            const unsigned short* tb = st_ + (nt2 * 32 + l31) * SEMBT_STRIDE + hi * 8;
#pragma unroll
            for (int ks2 = 0; ks2 < 4; ++ks2) {
                bf16x8 ta = *(const bf16x8*)(tb + ks2 * 16);
                acc[nt2] = __builtin_amdgcn_mfma_f32_32x32x16_bf16(ta, pfrag[ks2], acc[nt2], 0, 0, 0);
            }
        }

        // ---- stage tile it+1 into buf[cur^1]; issue loads for tile it+2 ----
        if (it + 1 < ITERS) {
            unsigned short* dA = s_embA[cur ^ 1] + srow * SEMB_STRIDE + sq3 * 32;
            unsigned short* dT = s_embTA[cur ^ 1] + sd * SEMBT_STRIDE + sh * 32;
#pragma unroll
            for (int u = 0; u < 4; ++u) *(bf16x8*)(dA + u * 8) = rA[u];
#pragma unroll
            for (int u = 0; u < 4; ++u) *(bf16x8*)(dT + u * 8) = rT[u];
            if (it + 2 < ITERS) {
                const int z2 = z_base + (it + 2) * TZ;
                const unsigned short* srcR = embR + (size_t)(z2 + srow) * D_SZ + sq3 * 32;
                const unsigned short* srcT = embT + (size_t)sd * Z_SZ + z2 + sh * 32;
#pragma unroll
                for (int u = 0; u < 4; ++u) { rA[u] = *(const bf16x8*)(srcR + u * 8); }
#pragma unroll
                for (int u = 0; u < 4; ++u) { rT[u] = *(const bf16x8*)(srcT + u * 8); }
            }
        }

        mv = mvn;
        cur ^= 1;
    }

    // ---- epilogue (cnt already full per row; identical in both hi lanes) ----
    {
        float* orow = ws + WS_O + ((size_t)ch * B_SZ + brow) * D_SZ;
#pragma unroll
        for (int nt2 = 0; nt2 < 4; ++nt2) {
#pragma unroll
            for (int g = 0; g < 4; ++g) {
                f32x4 v;
                v[0] = acc[nt2][4*g+0]; v[1] = acc[nt2][4*g+1];
                v[2] = acc[nt2][4*g+2]; v[3] = acc[nt2][4*g+3];
                *(f32x4*)(orow + nt2 * 32 + g * 8 + hi * 4) = v;   // d = 32nt2+8g+4hi+e
            }
        }
    }
    if (lane < 32) {
        ws[WS_M + ch * B_SZ + brow] = m_s;
        ws[WS_L + ch * B_SZ + brow] = l_s;
        ws[WS_C + ch * B_SZ + brow] = (float)cnt;
    }
}

__global__ __launch_bounds__(128) void attn_reduce(
    const float* __restrict__ ws, float* __restrict__ out)
{
    const int b = blockIdx.x;
    const int d = threadIdx.x;
    const float* mP = ws + WS_M;
    const float* lP = ws + WS_L;
    const float* cP = ws + WS_C;

    float M = -1e30f;
#pragma unroll
    for (int c = 0; c < NZ; ++c) M = fmaxf(M, mP[c * B_SZ + b]);

    float L = 0.f, C = 0.f, acc = 0.f;
#pragma unroll
    for (int c = 0; c < NZ; ++c) {
        float w = EXP2F(mP[c * B_SZ + b] - M);
        L += lP[c * B_SZ + b] * w;
        C += cP[c * B_SZ + b];
        acc += ws[WS_O + ((size_t)c * B_SZ + b) * D_SZ + d] * w;
    }
    float cntv = fmaxf(C, 1.0f);
    out[(size_t)b * D_SZ + d] = (L > 0.f) ? acc / (L * cntv) : 0.f;
}

extern "C" void kernel_launch(void* const* d_in, const int* in_sizes, int n_in,
                              void* d_out, int out_size, void* d_ws, size_t ws_size,
                              hipStream_t stream) {
    (void)in_sizes; (void)n_in; (void)out_size; (void)ws_size;
    const int*   zs  = (const int*)  d_in[0];
    const float* ctx = (const float*)d_in[1];
    const float* emb = (const float*)d_in[2];
    float* out = (float*)d_out;
    float* ws  = (float*)d_ws;

    unsigned short* embR  = (unsigned short*)(ws + WS_TAB);
    unsigned short* embT  = embR + (size_t)Z_SZ * D_SZ;
    uint32_t*       maskp = (uint32_t*)(embT + (size_t)Z_SZ * D_SZ);

    prep<<<NB_MASK + NB_TAB, 256, 0, stream>>>(zs, emb, embR, embT, maskp);

    dim3 grid1(B_SZ / TBLK, NZ);   // (8, 64): 512 blocks = 2/CU
    attn_part<<<grid1, 256, 0, stream>>>(maskp, ctx, embR, embT, ws);
    attn_reduce<<<B_SZ, 128, 0, stream>>>(ws, out);
}

// Round 12
// 242.907 us; speedup vs baseline: 1.0471x; 1.0471x over previous
//
#include <hip/hip_runtime.h>
#include <stdint.h>

// Problem constants
#define B_SZ 1024
#define Z_SZ 32768
#define D_SZ 128
#define NZ   64                 // z chunks (split-Z)
#define CZ   (Z_SZ / NZ)        // 512 z per chunk
#define TZ   64                 // z per inner tile
#define ITERS (CZ / TZ)         // 8
#define TBLK 128                // batch rows per block (4 waves x 32)
#define NWAVE 4
#define WROWS 32                // batch rows per wave (32x32 MFMA cols)

// LDS strides (elements). Row byte-strides must be 16B multiples for ds_read_b128,
// and every stride must be >= the row's element count.
#define SEMB_STRIDE  136        // 64 x 136 bf16 (row-major emb tile), 272B rows
#define SEMBT_STRIDE 72         // 128 x 72 bf16 (transposed emb tile), 144B rows
#define ST_STRIDE    136        // prep transpose staging rows hold 128 elems
#define SO_STRIDE    132        // epilogue f32 scratch row stride (128 floats + pad)

// LDS pool sizes (elements)
#define ASZ (TZ * SEMB_STRIDE)        // 8704 elems per A buffer
#define TSZ (D_SZ * SEMBT_STRIDE)     // 9216 elems per T buffer
#define ALL_SZ (2 * ASZ + 2 * TSZ)    // 35840 elems = 71680 B
// epilogue scratch: 128 * SO_STRIDE * 4 B = 67584 B  <= 71680 B  (fits, guaranteed)

#define NB_TAB  (Z_SZ / 64)     // 512 blocks build bf16 tables

// Workspace layout (float offsets)
#define WS_O   0                              // [NZ][B][D]  (33.5 MB)
#define WS_M   (NZ * B_SZ * D_SZ)             // [NZ][B]
#define WS_L   (WS_M + NZ * B_SZ)
#define WS_C   (WS_L + NZ * B_SZ)
#define WS_TAB (WS_C + NZ * B_SZ)             // embR [Z][D] bf16, embT [D][Z] bf16

typedef short bf16x8  __attribute__((ext_vector_type(8)));
typedef float f32x4   __attribute__((ext_vector_type(4)));
typedef float f32x16  __attribute__((ext_vector_type(16)));

#if __has_builtin(__builtin_amdgcn_exp2f)
#define EXP2F(x) __builtin_amdgcn_exp2f(x)
#else
#define EXP2F(x) exp2f(x)
#endif

__device__ __forceinline__ unsigned short f2bf(float f) {
    union { float f; uint32_t u; } v; v.f = f;
    uint32_t u = v.u;
    u = (u + 0x7FFFu + ((u >> 16) & 1u)) >> 16;   // RNE truncate to bf16
    return (unsigned short)u;
}
__device__ __forceinline__ uint32_t packbf(float a, float b) {
    return (uint32_t)f2bf(a) | ((uint32_t)f2bf(b) << 16);
}

// ---------------------------------------------------------------------------
// Prep: emb f32 [Z][D] -> bf16 embR [Z][D] and embT [D][Z]  (one block / 64 z)
// ---------------------------------------------------------------------------
__global__ __launch_bounds__(256) void prep(
    const float*    __restrict__ emb,
    unsigned short* __restrict__ embR,
    unsigned short* __restrict__ embT)
{
    __shared__ __align__(16) unsigned short st[64 * ST_STRIDE];
    const int z0 = blockIdx.x * 64;
    const int t  = threadIdx.x;
    {
        const int r = t >> 2, q = t & 3;
        const float* src = emb + (size_t)(z0 + r) * D_SZ + q * 32;
        unsigned short* dR = embR + (size_t)(z0 + r) * D_SZ + q * 32;
        unsigned short* dL = st + r * ST_STRIDE + q * 32;
#pragma unroll
        for (int u = 0; u < 8; ++u) {
            float4 x = *(const float4*)(src + 4 * u);
            ushort4 h;
            h.x = f2bf(x.x); h.y = f2bf(x.y); h.z = f2bf(x.z); h.w = f2bf(x.w);
            *(ushort4*)(dR + 4 * u) = h;
            *(ushort4*)(dL + 4 * u) = h;
        }
    }
    __syncthreads();
    {
        const int lane = t & 63, w = t >> 6;
#pragma unroll
        for (int i = 0; i < 4; ++i) {
            const int d = w * 32 + i * 8 + (lane >> 3);   // 0..127
            const int c = lane & 7;                       // 8-z chunk
            bf16x8 v;
#pragma unroll
            for (int k = 0; k < 8; ++k) v[k] = (short)st[(c * 8 + k) * ST_STRIDE + d];
            *(bf16x8*)(embT + (size_t)d * Z_SZ + z0 + c * 8) = v;
        }
    }
}

// ---------------------------------------------------------------------------
// attn_part (R9 structure): 32x32x16 MFMA, double-buffered LDS, ONE barrier/tile,
//   in-register P exchange, int4 direct masks (prefetched), PLUS:
//   - XCD work-swizzle: all 8 bg-blocks of a chunk share one XCD's L2
//   - write-coalesced epilogue via LDS f32 scratch carved from the SINGLE
//     explicitly-sized pool s_all (scratch 67584 B <= pool 71680 B)
// ---------------------------------------------------------------------------
__global__ __launch_bounds__(256, 2) void attn_part(
    const int*            __restrict__ zs,
    const float*          __restrict__ ctx,
    const unsigned short* __restrict__ embR,
    const unsigned short* __restrict__ embT,
    float*                __restrict__ ws)
{
    __shared__ __align__(16) unsigned short s_all[ALL_SZ];   // 71680 B pool

    const int tid  = threadIdx.x;
    const int lane = tid & 63;
    const int l31  = lane & 31;
    const int hi   = lane >> 5;

    // XCD work-swizzle: lid%8 == ch%8 for every block of chunk ch -> same XCD L2
    const int lid = blockIdx.y * 8 + blockIdx.x;   // 0..511, bijective
    const int ch  = lid & 63;                      // 0..63 z-chunk
    const int bg  = lid >> 6;                      // 0..7 batch group
    const int z_base = ch * CZ;
    const int wb0    = bg * TBLK + (tid >> 6) * WROWS;
    const int brow   = wb0 + l31;             // this lane's batch row (32 rows/wave)

    // staging thread mappings (256 threads, 64B each per tile)
    const int srow = tid >> 2, sq3 = tid & 3;   // row tile: row, 32-elem seg
    const int sd   = tid >> 1, sh  = tid & 1;   // transposed tile: d-row, 32-z seg

    const int* zrow = zs + (size_t)brow * Z_SZ + hi * 4;   // lane's mask base

    // ---- ctx B-fragments, scaled by log2(e)/sqrt(D) (base-2 softmax), in regs ----
    bf16x8 afrag[8];
    {
        const float scale = (float)(1.4426950408889634 * 0.08838834764831845);
        const float* crow = ctx + (size_t)brow * D_SZ;
#pragma unroll
        for (int ks = 0; ks < 8; ++ks) {
            const float* p = crow + ks * 16 + hi * 8;
            float4 x0 = *(const float4*)(p);
            float4 x1 = *(const float4*)(p + 4);
            bf16x8 a;
            a[0] = (short)f2bf(x0.x * scale); a[1] = (short)f2bf(x0.y * scale);
            a[2] = (short)f2bf(x0.z * scale); a[3] = (short)f2bf(x0.w * scale);
            a[4] = (short)f2bf(x1.x * scale); a[5] = (short)f2bf(x1.y * scale);
            a[6] = (short)f2bf(x1.z * scale); a[7] = (short)f2bf(x1.w * scale);
            afrag[ks] = a;
        }
    }

    // ---- per-lane online-softmax state ----
    float m_s = -1e30f, l_s = 0.f;
    int   cnt = 0;      // this lane's 32 z'/tile; + partner(hi^1) at epilogue
    f32x16 acc[4];
#pragma unroll
    for (int n = 0; n < 4; ++n)
#pragma unroll
        for (int e = 0; e < 16; ++e) acc[n][e] = 0.f;

    // ---- staging registers (tables) + 2-deep mask prefetch ----
    bf16x8 rA[4], rT[4];
    int4   mc[2][4], mn[2][4];

    // prologue: load tile 0 -> regs; write buf0; load tile 1 -> regs; masks tile 0
    {
        const unsigned short* srcR = embR + (size_t)(z_base + srow) * D_SZ + sq3 * 32;
        const unsigned short* srcT = embT + (size_t)sd * Z_SZ + z_base + sh * 32;
#pragma unroll
        for (int u = 0; u < 4; ++u) { rA[u] = *(const bf16x8*)(srcR + u * 8); }
#pragma unroll
        for (int u = 0; u < 4; ++u) { rT[u] = *(const bf16x8*)(srcT + u * 8); }
#pragma unroll
        for (int nt = 0; nt < 2; ++nt)
#pragma unroll
            for (int g = 0; g < 4; ++g)
                mc[nt][g] = *(const int4*)(zrow + z_base + nt * 32 + g * 8);
    }
    {
        unsigned short* dA = s_all + srow * SEMB_STRIDE + sq3 * 32;               // buf A0
        unsigned short* dT = s_all + 2 * ASZ + sd * SEMBT_STRIDE + sh * 32;       // buf T0
#pragma unroll
        for (int u = 0; u < 4; ++u) *(bf16x8*)(dA + u * 8) = rA[u];
#pragma unroll
        for (int u = 0; u < 4; ++u) *(bf16x8*)(dT + u * 8) = rT[u];
    }
    if (ITERS > 1) {
        const int z1 = z_base + TZ;
        const unsigned short* srcR = embR + (size_t)(z1 + srow) * D_SZ + sq3 * 32;
        const unsigned short* srcT = embT + (size_t)sd * Z_SZ + z1 + sh * 32;
#pragma unroll
        for (int u = 0; u < 4; ++u) { rA[u] = *(const bf16x8*)(srcR + u * 8); }
#pragma unroll
        for (int u = 0; u < 4; ++u) { rT[u] = *(const bf16x8*)(srcT + u * 8); }
    }

    int cur = 0;
    for (int it = 0; it < ITERS; ++it) {
        __syncthreads();   // buf[cur] writes visible; prior reads of buf[cur^1] done

        // ---- issue next tile's mask loads (HBM); consumed NEXT iteration ----
        if (it + 1 < ITERS) {
            const int z0n = z_base + (it + 1) * TZ;
#pragma unroll
            for (int nt = 0; nt < 2; ++nt)
#pragma unroll
                for (int g = 0; g < 4; ++g)
                    mn[nt][g] = *(const int4*)(zrow + z0n + nt * 32 + g * 8);
        }

        const unsigned short* se  = s_all + cur * ASZ;
        const unsigned short* st_ = s_all + 2 * ASZ + cur * TSZ;

        // ---- GEMM1 (32x32x16): lane gets S[b=l31][z' = 32nt + 8g + 4hi + e] ----
        f32x16 sfr[2];
#pragma unroll
        for (int nt = 0; nt < 2; ++nt) {
            f32x16 c;
#pragma unroll
            for (int e = 0; e < 16; ++e) c[e] = 0.f;
            const unsigned short* bb = se + (nt * 32 + l31) * SEMB_STRIDE + hi * 8;
#pragma unroll
            for (int ks = 0; ks < 8; ++ks) {
                bf16x8 ef = *(const bf16x8*)(bb + ks * 16);
                c = __builtin_amdgcn_mfma_f32_32x32x16_bf16(ef, afrag[ks], c, 0, 0, 0);
            }
            sfr[nt] = c;
        }

        // ---- mask bits: reg r=4g+e of tile nt <-> mc[nt][g] component e ----
        int bit[2][16];
#pragma unroll
        for (int nt = 0; nt < 2; ++nt) {
#pragma unroll
            for (int g = 0; g < 4; ++g) {
                bit[nt][4*g+0] = (mc[nt][g].x > 0) ? 1 : 0;
                bit[nt][4*g+1] = (mc[nt][g].y > 0) ? 1 : 0;
                bit[nt][4*g+2] = (mc[nt][g].z > 0) ? 1 : 0;
                bit[nt][4*g+3] = (mc[nt][g].w > 0) ? 1 : 0;
                cnt += bit[nt][4*g+0] + bit[nt][4*g+1] + bit[nt][4*g+2] + bit[nt][4*g+3];
            }
        }

        // ---- masked max: in-lane tree over 32 + ONE cross-half shuffle ----
        float tm = -1e30f;
#pragma unroll
        for (int nt = 0; nt < 2; ++nt) {
#pragma unroll
            for (int r = 0; r < 16; r += 4) {
                float a0 = bit[nt][r+0] ? sfr[nt][r+0] : -1e30f;
                float a1 = bit[nt][r+1] ? sfr[nt][r+1] : -1e30f;
                float a2 = bit[nt][r+2] ? sfr[nt][r+2] : -1e30f;
                float a3 = bit[nt][r+3] ? sfr[nt][r+3] : -1e30f;
                tm = fmaxf(tm, fmaxf(fmaxf(a0, a1), fmaxf(a2, a3)));
            }
        }
        tm = fmaxf(tm, __shfl_xor(tm, 32));

        // ---- T13 defer-max ----
        if (__any(tm > m_s + 8.f)) {
            float mnew = fmaxf(m_s, tm);
            float al = EXP2F(m_s - mnew);
            m_s = mnew;
            l_s *= al;
#pragma unroll
            for (int n = 0; n < 4; ++n)
#pragma unroll
                for (int e = 0; e < 16; ++e) acc[n][e] *= al;
        }

        // ---- P = mask ? 2^(S-m) : 0 ; pack to u32 bf16-pairs (in-register) ----
        uint32_t q[8][2];
        float ps = 0.f;
#pragma unroll
        for (int nt = 0; nt < 2; ++nt) {
#pragma unroll
            for (int g = 0; g < 4; ++g) {
                float p0 = bit[nt][4*g+0] ? EXP2F(sfr[nt][4*g+0] - m_s) : 0.f;
                float p1 = bit[nt][4*g+1] ? EXP2F(sfr[nt][4*g+1] - m_s) : 0.f;
                float p2 = bit[nt][4*g+2] ? EXP2F(sfr[nt][4*g+2] - m_s) : 0.f;
                float p3 = bit[nt][4*g+3] ? EXP2F(sfr[nt][4*g+3] - m_s) : 0.f;
                ps += (p0 + p1) + (p2 + p3);
                q[4*nt+g][0] = packbf(p0, p1);
                q[4*nt+g][1] = packbf(p2, p3);
            }
        }
        ps += __shfl_xor(ps, 32);
        l_s += ps;

        // ---- assemble GEMM2 B-frags: swap partner half-groups via shfl_xor(32) ----
        bf16x8 pfrag[4];
#pragma unroll
        for (int ks2 = 0; ks2 < 4; ++ks2) {
            uint32_t s0 = hi ? q[2*ks2][0] : q[2*ks2+1][0];   // what partner needs
            uint32_t s1 = hi ? q[2*ks2][1] : q[2*ks2+1][1];
            uint32_t r0 = (uint32_t)__shfl_xor((int)s0, 32);
            uint32_t r1 = (uint32_t)__shfl_xor((int)s1, 32);
            union { uint32_t u[4]; bf16x8 v; } P;
            P.u[0] = hi ? r0 : q[2*ks2][0];     // j=0,1
            P.u[1] = hi ? r1 : q[2*ks2][1];     // j=2,3
            P.u[2] = hi ? q[2*ks2+1][0] : r0;   // j=4,5
            P.u[3] = hi ? q[2*ks2+1][1] : r1;   // j=6,7
            pfrag[ks2] = P.v;
        }

        // ---- GEMM2 (O^T, 32x32x16): acc[nt2] += embT_rows @ P^T ----
#pragma unroll
        for (int nt2 = 0; nt2 < 4; ++nt2) {
            const unsigned short* tb = st_ + (nt2 * 32 + l31) * SEMBT_STRIDE + hi * 8;
#pragma unroll
            for (int ks2 = 0; ks2 < 4; ++ks2) {
                bf16x8 ta = *(const bf16x8*)(tb + ks2 * 16);
                acc[nt2] = __builtin_amdgcn_mfma_f32_32x32x16_bf16(ta, pfrag[ks2], acc[nt2], 0, 0, 0);
            }
        }

        // ---- stage tile it+1 into buf[cur^1]; issue loads for tile it+2 ----
        if (it + 1 < ITERS) {
            unsigned short* dA = s_all + (cur ^ 1) * ASZ + srow * SEMB_STRIDE + sq3 * 32;
            unsigned short* dT = s_all + 2 * ASZ + (cur ^ 1) * TSZ + sd * SEMBT_STRIDE + sh * 32;
#pragma unroll
            for (int u = 0; u < 4; ++u) *(bf16x8*)(dA + u * 8) = rA[u];
#pragma unroll
            for (int u = 0; u < 4; ++u) *(bf16x8*)(dT + u * 8) = rT[u];
            if (it + 2 < ITERS) {
                const int z2 = z_base + (it + 2) * TZ;
                const unsigned short* srcR = embR + (size_t)(z2 + srow) * D_SZ + sq3 * 32;
                const unsigned short* srcT = embT + (size_t)sd * Z_SZ + z2 + sh * 32;
#pragma unroll
                for (int u = 0; u < 4; ++u) { rA[u] = *(const bf16x8*)(srcR + u * 8); }
#pragma unroll
                for (int u = 0; u < 4; ++u) { rT[u] = *(const bf16x8*)(srcT + u * 8); }
            }
        }

#pragma unroll
        for (int nt = 0; nt < 2; ++nt)
#pragma unroll
            for (int g = 0; g < 4; ++g) mc[nt][g] = mn[nt][g];
        cur ^= 1;
    }

    // ---- epilogue: acc -> LDS f32 scratch (in s_all pool) -> full-line O stores ----
    __syncthreads();   // all table-LDS reads complete; whole pool reusable
    {
        float* fs = (float*)s_all;                // [128][SO_STRIDE] f32 = 67584 B <= 71680 B
        const int rl = (tid >> 6) * WROWS + l31;  // local row 0..127
#pragma unroll
        for (int nt2 = 0; nt2 < 4; ++nt2) {
#pragma unroll
            for (int g = 0; g < 4; ++g) {
                f32x4 v;
                v[0] = acc[nt2][4*g+0]; v[1] = acc[nt2][4*g+1];
                v[2] = acc[nt2][4*g+2]; v[3] = acc[nt2][4*g+3];
                *(f32x4*)(fs + rl * SO_STRIDE + nt2 * 32 + g * 8 + hi * 4) = v;
            }
        }
    }
    __syncthreads();
    {
        const float* fs = (const float*)s_all;
        const int row = tid >> 1, half = tid & 1;     // 2 threads per row, 256B each
        const float* src = fs + row * SO_STRIDE + half * 64;
        float* dst = ws + WS_O + ((size_t)ch * B_SZ + bg * TBLK + row) * D_SZ + half * 64;
#pragma unroll
        for (int u = 0; u < 16; ++u)
            *(f32x4*)(dst + u * 4) = *(const f32x4*)(src + u * 4);
    }
    cnt += __shfl_xor(cnt, 32);
    if (lane < 32) {
        ws[WS_M + ch * B_SZ + brow] = m_s;
        ws[WS_L + ch * B_SZ + brow] = l_s;
        ws[WS_C + ch * B_SZ + brow] = (float)cnt;
    }
}

__global__ __launch_bounds__(128) void attn_reduce(
    const float* __restrict__ ws, float* __restrict__ out)
{
    const int b = blockIdx.x;
    const int d = threadIdx.x;
    const float* mP = ws + WS_M;
    const float* lP = ws + WS_L;
    const float* cP = ws + WS_C;

    float M = -1e30f;
#pragma unroll
    for (int c = 0; c < NZ; ++c) M = fmaxf(M, mP[c * B_SZ + b]);

    float L = 0.f, C = 0.f, acc = 0.f;
#pragma unroll
    for (int c = 0; c < NZ; ++c) {
        float w = EXP2F(mP[c * B_SZ + b] - M);
        L += lP[c * B_SZ + b] * w;
        C += cP[c * B_SZ + b];
        acc += ws[WS_O + ((size_t)c * B_SZ + b) * D_SZ + d] * w;
    }
    float cntv = fmaxf(C, 1.0f);
    out[(size_t)b * D_SZ + d] = (L > 0.f) ? acc / (L * cntv) : 0.f;
}

extern "C" void kernel_launch(void* const* d_in, const int* in_sizes, int n_in,
                              void* d_out, int out_size, void* d_ws, size_t ws_size,
                              hipStream_t stream) {
    (void)in_sizes; (void)n_in; (void)out_size; (void)ws_size;
    const int*   zs  = (const int*)  d_in[0];
    const float* ctx = (const float*)d_in[1];
    const float* emb = (const float*)d_in[2];
    float* out = (float*)d_out;
    float* ws  = (float*)d_ws;

    unsigned short* embR = (unsigned short*)(ws + WS_TAB);
    unsigned short* embT = embR + (size_t)Z_SZ * D_SZ;

    prep<<<NB_TAB, 256, 0, stream>>>(emb, embR, embT);

    dim3 grid1(B_SZ / TBLK, NZ);   // (8, 64): 512 blocks = 2/CU; work swizzled inside
    attn_part<<<grid1, 256, 0, stream>>>(zs, ctx, embR, embT, ws);
    attn_reduce<<<B_SZ, 128, 0, stream>>>(ws, out);
}

// Round 14
// 238.732 us; speedup vs baseline: 1.0654x; 1.0175x over previous
//
#include <hip/hip_runtime.h>
#include <stdint.h>

// Problem constants
#define B_SZ 1024
#define Z_SZ 32768
#define D_SZ 128
#define NZ   64                 // z chunks (split-Z)
#define CZ   (Z_SZ / NZ)        // 512 z per chunk
#define TZ   64                 // z per inner tile
#define ITERS (CZ / TZ)         // 8
#define TBLK 128                // batch rows per block (4 waves x 32)
#define NWAVE 4
#define WROWS 32                // batch rows per wave (32x32 MFMA cols)

// LDS strides (elements). Row byte-strides must be 16B multiples for ds_read_b128,
// and every stride must be >= the row's element count.
#define SEMB_STRIDE  136        // 64 x 136 bf16 (row-major emb tile), 272B rows
#define SEMBT_STRIDE 72         // 128 x 72 bf16 (transposed emb tile), 144B rows
#define ST_STRIDE    136        // prep transpose staging rows hold 128 elems
#define SO_STRIDE    132        // epilogue f32 scratch row stride (128 floats + pad)

// LDS pool sizes (elements)
#define ASZ (TZ * SEMB_STRIDE)        // 8704 elems per A buffer
#define TSZ (D_SZ * SEMBT_STRIDE)     // 9216 elems per T buffer
#define ALL_SZ (2 * ASZ + 2 * TSZ)    // 35840 elems = 71680 B
// epilogue scratch: 128 * SO_STRIDE * 4 B = 67584 B  <= 71680 B  (fits, guaranteed)

#define NB_TAB  (Z_SZ / 64)     // 512 blocks build bf16 tables

// Workspace layout (float offsets)
#define WS_O   0                              // [NZ][B][D]  (33.5 MB)
#define WS_M   (NZ * B_SZ * D_SZ)             // [NZ][B]
#define WS_L   (WS_M + NZ * B_SZ)
#define WS_C   (WS_L + NZ * B_SZ)
#define WS_TAB (WS_C + NZ * B_SZ)             // embR [Z][D] bf16, embT [D][Z] bf16

typedef short bf16x8  __attribute__((ext_vector_type(8)));
typedef float f32x4   __attribute__((ext_vector_type(4)));
typedef float f32x16  __attribute__((ext_vector_type(16)));

#if __has_builtin(__builtin_amdgcn_exp2f)
#define EXP2F(x) __builtin_amdgcn_exp2f(x)
#else
#define EXP2F(x) exp2f(x)
#endif

__device__ __forceinline__ unsigned short f2bf(float f) {
    union { float f; uint32_t u; } v; v.f = f;
    uint32_t u = v.u;
    u = (u + 0x7FFFu + ((u >> 16) & 1u)) >> 16;   // RNE truncate to bf16
    return (unsigned short)u;
}
__device__ __forceinline__ uint32_t packbf(float a, float b) {
    return (uint32_t)f2bf(a) | ((uint32_t)f2bf(b) << 16);
}

// ---------------------------------------------------------------------------
// Prep: emb f32 [Z][D] -> bf16 embR [Z][D] and embT [D][Z]  (one block / 64 z)
// ---------------------------------------------------------------------------
__global__ __launch_bounds__(256) void prep(
    const float*    __restrict__ emb,
    unsigned short* __restrict__ embR,
    unsigned short* __restrict__ embT)
{
    __shared__ __align__(16) unsigned short st[64 * ST_STRIDE];
    const int z0 = blockIdx.x * 64;
    const int t  = threadIdx.x;
    {
        const int r = t >> 2, q = t & 3;
        const float* src = emb + (size_t)(z0 + r) * D_SZ + q * 32;
        unsigned short* dR = embR + (size_t)(z0 + r) * D_SZ + q * 32;
        unsigned short* dL = st + r * ST_STRIDE + q * 32;
#pragma unroll
        for (int u = 0; u < 8; ++u) {
            float4 x = *(const float4*)(src + 4 * u);
            ushort4 h;
            h.x = f2bf(x.x); h.y = f2bf(x.y); h.z = f2bf(x.z); h.w = f2bf(x.w);
            *(ushort4*)(dR + 4 * u) = h;
            *(ushort4*)(dL + 4 * u) = h;
        }
    }
    __syncthreads();
    {
        const int lane = t & 63, w = t >> 6;
#pragma unroll
        for (int i = 0; i < 4; ++i) {
            const int d = w * 32 + i * 8 + (lane >> 3);   // 0..127
            const int c = lane & 7;                       // 8-z chunk
            bf16x8 v;
#pragma unroll
            for (int k = 0; k < 8; ++k) v[k] = (short)st[(c * 8 + k) * ST_STRIDE + d];
            *(bf16x8*)(embT + (size_t)d * Z_SZ + z0 + c * 8) = v;
        }
    }
}

// ---------------------------------------------------------------------------
// attn_part (R9 structure, no XCD swizzle): 32x32x16 MFMA, double-buffered LDS,
//   ONE barrier/tile, in-register P exchange, int4 direct masks (prefetched),
//   write-coalesced epilogue via the explicitly-sized s_all LDS pool.
// ---------------------------------------------------------------------------
__global__ __launch_bounds__(256, 2) void attn_part(
    const int*            __restrict__ zs,
    const float*          __restrict__ ctx,
    const unsigned short* __restrict__ embR,
    const unsigned short* __restrict__ embT,
    float*                __restrict__ ws)
{
    __shared__ __align__(16) unsigned short s_all[ALL_SZ];   // 71680 B pool

    const int tid  = threadIdx.x;
    const int lane = tid & 63;
    const int l31  = lane & 31;
    const int hi   = lane >> 5;

    const int bg     = blockIdx.x;            // 0..7 batch group (R9 mapping, no swizzle)
    const int ch     = blockIdx.y;            // 0..63 z-chunk
    const int z_base = ch * CZ;
    const int wb0    = bg * TBLK + (tid >> 6) * WROWS;
    const int brow   = wb0 + l31;             // this lane's batch row (32 rows/wave)

    // staging thread mappings (256 threads, 64B each per tile)
    const int srow = tid >> 2, sq3 = tid & 3;   // row tile: row, 32-elem seg
    const int sd   = tid >> 1, sh  = tid & 1;   // transposed tile: d-row, 32-z seg

    const int* zrow = zs + (size_t)brow * Z_SZ + hi * 4;   // lane's mask base

    // ---- ctx B-fragments, scaled by log2(e)/sqrt(D) (base-2 softmax), in regs ----
    bf16x8 afrag[8];
    {
        const float scale = (float)(1.4426950408889634 * 0.08838834764831845);
        const float* crow = ctx + (size_t)brow * D_SZ;
#pragma unroll
        for (int ks = 0; ks < 8; ++ks) {
            const float* p = crow + ks * 16 + hi * 8;
            float4 x0 = *(const float4*)(p);
            float4 x1 = *(const float4*)(p + 4);
            bf16x8 a;
            a[0] = (short)f2bf(x0.x * scale); a[1] = (short)f2bf(x0.y * scale);
            a[2] = (short)f2bf(x0.z * scale); a[3] = (short)f2bf(x0.w * scale);
            a[4] = (short)f2bf(x1.x * scale); a[5] = (short)f2bf(x1.y * scale);
            a[6] = (short)f2bf(x1.z * scale); a[7] = (short)f2bf(x1.w * scale);
            afrag[ks] = a;
        }
    }

    // ---- per-lane online-softmax state ----
    float m_s = -1e30f, l_s = 0.f;
    int   cnt = 0;      // this lane's 32 z'/tile; + partner(hi^1) at epilogue
    f32x16 acc[4];
#pragma unroll
    for (int n = 0; n < 4; ++n)
#pragma unroll
        for (int e = 0; e < 16; ++e) acc[n][e] = 0.f;

    // ---- staging registers (tables) + 2-deep mask prefetch ----
    bf16x8 rA[4], rT[4];
    int4   mc[2][4], mn[2][4];

    // prologue: load tile 0 -> regs; write buf0; load tile 1 -> regs; masks tile 0
    {
        const unsigned short* srcR = embR + (size_t)(z_base + srow) * D_SZ + sq3 * 32;
        const unsigned short* srcT = embT + (size_t)sd * Z_SZ + z_base + sh * 32;
#pragma unroll
        for (int u = 0; u < 4; ++u) { rA[u] = *(const bf16x8*)(srcR + u * 8); }
#pragma unroll
        for (int u = 0; u < 4; ++u) { rT[u] = *(const bf16x8*)(srcT + u * 8); }
#pragma unroll
        for (int nt = 0; nt < 2; ++nt)
#pragma unroll
            for (int g = 0; g < 4; ++g)
                mc[nt][g] = *(const int4*)(zrow + z_base + nt * 32 + g * 8);
    }
    {
        unsigned short* dA = s_all + srow * SEMB_STRIDE + sq3 * 32;               // buf A0
        unsigned short* dT = s_all + 2 * ASZ + sd * SEMBT_STRIDE + sh * 32;       // buf T0
#pragma unroll
        for (int u = 0; u < 4; ++u) *(bf16x8*)(dA + u * 8) = rA[u];
#pragma unroll
        for (int u = 0; u < 4; ++u) *(bf16x8*)(dT + u * 8) = rT[u];
    }
    if (ITERS > 1) {
        const int z1 = z_base + TZ;
        const unsigned short* srcR = embR + (size_t)(z1 + srow) * D_SZ + sq3 * 32;
        const unsigned short* srcT = embT + (size_t)sd * Z_SZ + z1 + sh * 32;
#pragma unroll
        for (int u = 0; u < 4; ++u) { rA[u] = *(const bf16x8*)(srcR + u * 8); }
#pragma unroll
        for (int u = 0; u < 4; ++u) { rT[u] = *(const bf16x8*)(srcT + u * 8); }
    }

    int cur = 0;
    for (int it = 0; it < ITERS; ++it) {
        __syncthreads();   // buf[cur] writes visible; prior reads of buf[cur^1] done

        // ---- issue next tile's mask loads (HBM); consumed NEXT iteration ----
        if (it + 1 < ITERS) {
            const int z0n = z_base + (it + 1) * TZ;
#pragma unroll
            for (int nt = 0; nt < 2; ++nt)
#pragma unroll
                for (int g = 0; g < 4; ++g)
                    mn[nt][g] = *(const int4*)(zrow + z0n + nt * 32 + g * 8);
        }

        const unsigned short* se  = s_all + cur * ASZ;
        const unsigned short* st_ = s_all + 2 * ASZ + cur * TSZ;

        // ---- GEMM1 (32x32x16): lane gets S[b=l31][z' = 32nt + 8g + 4hi + e] ----
        f32x16 sfr[2];
#pragma unroll
        for (int nt = 0; nt < 2; ++nt) {
            f32x16 c;
#pragma unroll
            for (int e = 0; e < 16; ++e) c[e] = 0.f;
            const unsigned short* bb = se + (nt * 32 + l31) * SEMB_STRIDE + hi * 8;
#pragma unroll
            for (int ks = 0; ks < 8; ++ks) {
                bf16x8 ef = *(const bf16x8*)(bb + ks * 16);
                c = __builtin_amdgcn_mfma_f32_32x32x16_bf16(ef, afrag[ks], c, 0, 0, 0);
            }
            sfr[nt] = c;
        }

        // ---- mask bits: reg r=4g+e of tile nt <-> mc[nt][g] component e ----
        int bit[2][16];
#pragma unroll
        for (int nt = 0; nt < 2; ++nt) {
#pragma unroll
            for (int g = 0; g < 4; ++g) {
                bit[nt][4*g+0] = (mc[nt][g].x > 0) ? 1 : 0;
                bit[nt][4*g+1] = (mc[nt][g].y > 0) ? 1 : 0;
                bit[nt][4*g+2] = (mc[nt][g].z > 0) ? 1 : 0;
                bit[nt][4*g+3] = (mc[nt][g].w > 0) ? 1 : 0;
                cnt += bit[nt][4*g+0] + bit[nt][4*g+1] + bit[nt][4*g+2] + bit[nt][4*g+3];
            }
        }

        // ---- masked max: in-lane tree over 32 + ONE cross-half shuffle ----
        float tm = -1e30f;
#pragma unroll
        for (int nt = 0; nt < 2; ++nt) {
#pragma unroll
            for (int r = 0; r < 16; r += 4) {
                float a0 = bit[nt][r+0] ? sfr[nt][r+0] : -1e30f;
                float a1 = bit[nt][r+1] ? sfr[nt][r+1] : -1e30f;
                float a2 = bit[nt][r+2] ? sfr[nt][r+2] : -1e30f;
                float a3 = bit[nt][r+3] ? sfr[nt][r+3] : -1e30f;
                tm = fmaxf(tm, fmaxf(fmaxf(a0, a1), fmaxf(a2, a3)));
            }
        }
        tm = fmaxf(tm, __shfl_xor(tm, 32));

        // ---- T13 defer-max ----
        if (__any(tm > m_s + 8.f)) {
            float mnew = fmaxf(m_s, tm);
            float al = EXP2F(m_s - mnew);
            m_s = mnew;
            l_s *= al;
#pragma unroll
            for (int n = 0; n < 4; ++n)
#pragma unroll
                for (int e = 0; e < 16; ++e) acc[n][e] *= al;
        }

        // ---- P = mask ? 2^(S-m) : 0 ; pack to u32 bf16-pairs (in-register) ----
        uint32_t q[8][2];
        float ps = 0.f;
#pragma unroll
        for (int nt = 0; nt < 2; ++nt) {
#pragma unroll
            for (int g = 0; g < 4; ++g) {
                float p0 = bit[nt][4*g+0] ? EXP2F(sfr[nt][4*g+0] - m_s) : 0.f;
                float p1 = bit[nt][4*g+1] ? EXP2F(sfr[nt][4*g+1] - m_s) : 0.f;
                float p2 = bit[nt][4*g+2] ? EXP2F(sfr[nt][4*g+2] - m_s) : 0.f;
                float p3 = bit[nt][4*g+3] ? EXP2F(sfr[nt][4*g+3] - m_s) : 0.f;
                ps += (p0 + p1) + (p2 + p3);
                q[4*nt+g][0] = packbf(p0, p1);
                q[4*nt+g][1] = packbf(p2, p3);
            }
        }
        ps += __shfl_xor(ps, 32);
        l_s += ps;

        // ---- assemble GEMM2 B-frags: swap partner half-groups via shfl_xor(32) ----
        bf16x8 pfrag[4];
#pragma unroll
        for (int ks2 = 0; ks2 < 4; ++ks2) {
            uint32_t s0 = hi ? q[2*ks2][0] : q[2*ks2+1][0];   // what partner needs
            uint32_t s1 = hi ? q[2*ks2][1] : q[2*ks2+1][1];
            uint32_t r0 = (uint32_t)__shfl_xor((int)s0, 32);
            uint32_t r1 = (uint32_t)__shfl_xor((int)s1, 32);
            union { uint32_t u[4]; bf16x8 v; } P;
            P.u[0] = hi ? r0 : q[2*ks2][0];     // j=0,1
            P.u[1] = hi ? r1 : q[2*ks2][1];     // j=2,3
            P.u[2] = hi ? q[2*ks2+1][0] : r0;   // j=4,5
            P.u[3] = hi ? q[2*ks2+1][1] : r1;   // j=6,7
            pfrag[ks2] = P.v;
        }

        // ---- GEMM2 (O^T, 32x32x16): acc[nt2] += embT_rows @ P^T ----
#pragma unroll
        for (int nt2 = 0; nt2 < 4; ++nt2) {
            const unsigned short* tb = st_ + (nt2 * 32 + l31) * SEMBT_STRIDE + hi * 8;
#pragma unroll
            for (int ks2 = 0; ks2 < 4; ++ks2) {
                bf16x8 ta = *(const bf16x8*)(tb + ks2 * 16);
                acc[nt2] = __builtin_amdgcn_mfma_f32_32x32x16_bf16(ta, pfrag[ks2], acc[nt2], 0, 0, 0);
            }
        }

        // ---- stage tile it+1 into buf[cur^1]; issue loads for tile it+2 ----
        if (it + 1 < ITERS) {
            unsigned short* dA = s_all + (cur ^ 1) * ASZ + srow * SEMB_STRIDE + sq3 * 32;
            unsigned short* dT = s_all + 2 * ASZ + (cur ^ 1) * TSZ + sd * SEMBT_STRIDE + sh * 32;
#pragma unroll
            for (int u = 0; u < 4; ++u) *(bf16x8*)(dA + u * 8) = rA[u];
#pragma unroll
            for (int u = 0; u < 4; ++u) *(bf16x8*)(dT + u * 8) = rT[u];
            if (it + 2 < ITERS) {
                const int z2 = z_base + (it + 2) * TZ;
                const unsigned short* srcR = embR + (size_t)(z2 + srow) * D_SZ + sq3 * 32;
                const unsigned short* srcT = embT + (size_t)sd * Z_SZ + z2 + sh * 32;
#pragma unroll
                for (int u = 0; u < 4; ++u) { rA[u] = *(const bf16x8*)(srcR + u * 8); }
#pragma unroll
                for (int u = 0; u < 4; ++u) { rT[u] = *(const bf16x8*)(srcT + u * 8); }
            }
        }

#pragma unroll
        for (int nt = 0; nt < 2; ++nt)
#pragma unroll
            for (int g = 0; g < 4; ++g) mc[nt][g] = mn[nt][g];
        cur ^= 1;
    }

    // ---- epilogue: acc -> LDS f32 scratch (in s_all pool) -> full-line O stores ----
    __syncthreads();   // all table-LDS reads complete; whole pool reusable
    {
        float* fs = (float*)s_all;                // [128][SO_STRIDE] f32 = 67584 B <= 71680 B
        const int rl = (tid >> 6) * WROWS + l31;  // local row 0..127
#pragma unroll
        for (int nt2 = 0; nt2 < 4; ++nt2) {
#pragma unroll
            for (int g = 0; g < 4; ++g) {
                f32x4 v;
                v[0] = acc[nt2][4*g+0]; v[1] = acc[nt2][4*g+1];
                v[2] = acc[nt2][4*g+2]; v[3] = acc[nt2][4*g+3];
                *(f32x4*)(fs + rl * SO_STRIDE + nt2 * 32 + g * 8 + hi * 4) = v;
            }
        }
    }
    __syncthreads();
    {
        const float* fs = (const float*)s_all;
        const int row = tid >> 1, half = tid & 1;     // 2 threads per row, 256B each
        const float* src = fs + row * SO_STRIDE + half * 64;
        float* dst = ws + WS_O + ((size_t)ch * B_SZ + bg * TBLK + row) * D_SZ + half * 64;
#pragma unroll
        for (int u = 0; u < 16; ++u)
            *(f32x4*)(dst + u * 4) = *(const f32x4*)(src + u * 4);
    }
    cnt += __shfl_xor(cnt, 32);
    if (lane < 32) {
        ws[WS_M + ch * B_SZ + brow] = m_s;
        ws[WS_L + ch * B_SZ + brow] = l_s;
        ws[WS_C + ch * B_SZ + brow] = (float)cnt;
    }
}

__global__ __launch_bounds__(128) void attn_reduce(
    const float* __restrict__ ws, float* __restrict__ out)
{
    const int b = blockIdx.x;
    const int d = threadIdx.x;
    const float* mP = ws + WS_M;
    const float* lP = ws + WS_L;
    const float* cP = ws + WS_C;

    float M = -1e30f;
#pragma unroll
    for (int c = 0; c < NZ; ++c) M = fmaxf(M, mP[c * B_SZ + b]);

    float L = 0.f, C = 0.f, acc = 0.f;
#pragma unroll
    for (int c = 0; c < NZ; ++c) {
        float w = EXP2F(mP[c * B_SZ + b] - M);
        L += lP[c * B_SZ + b] * w;
        C += cP[c * B_SZ + b];
        acc += ws[WS_O + ((size_t)c * B_SZ + b) * D_SZ + d] * w;
    }
    float cntv = fmaxf(C, 1.0f);
    out[(size_t)b * D_SZ + d] = (L > 0.f) ? acc / (L * cntv) : 0.f;
}

extern "C" void kernel_launch(void* const* d_in, const int* in_sizes, int n_in,
                              void* d_out, int out_size, void* d_ws, size_t ws_size,
                              hipStream_t stream) {
    (void)in_sizes; (void)n_in; (void)out_size; (void)ws_size;
    const int*   zs  = (const int*)  d_in[0];
    const float* ctx = (const float*)d_in[1];
    const float* emb = (const float*)d_in[2];
    float* out = (float*)d_out;
    float* ws  = (float*)d_ws;

    unsigned short* embR = (unsigned short*)(ws + WS_TAB);
    unsigned short* embT = embR + (size_t)Z_SZ * D_SZ;

    prep<<<NB_TAB, 256, 0, stream>>>(emb, embR, embT);

    dim3 grid1(B_SZ / TBLK, NZ);   // (8, 64): 512 blocks = 2/CU
    attn_part<<<grid1, 256, 0, stream>>>(zs, ctx, embR, embT, ws);
    attn_reduce<<<B_SZ, 128, 0, stream>>>(ws, out);
}